// Round 1
// baseline (7371.230 us; speedup 1.0000x reference)
//
#include <hip/hip_runtime.h>

#define N_NODES 500000
#define N_EDGES 8000000

__device__ __forceinline__ float leaky_f(float x) { return x > 0.0f ? x : 0.1f * x; }

// K1: h[s][i][c] = sum_k x[i][k] * W_s[k][c]   (3 sets), and deg[s][i] = 1.0 (self loop)
__global__ void k1_gemm_deginit(const float* __restrict__ x,
                                const float* __restrict__ Wp,
                                const float* __restrict__ Ws,
                                const float* __restrict__ Wv,
                                float* __restrict__ h,    // [3][N][5]
                                float* __restrict__ deg)  // [3][N]
{
    __shared__ float sW[3][25][5];
    int t = threadIdx.x;
    if (t < 125) {
        sW[0][t / 5][t % 5] = Wp[t];
        sW[1][t / 5][t % 5] = Ws[t];
        sW[2][t / 5][t % 5] = Wv[t];
    }
    __syncthreads();

    for (int i = blockIdx.x * blockDim.x + t; i < N_NODES; i += gridDim.x * blockDim.x) {
        float xi[25];
#pragma unroll
        for (int k = 0; k < 25; ++k) xi[k] = x[i * 25 + k];
#pragma unroll
        for (int s = 0; s < 3; ++s) {
            float acc[5] = {0.f, 0.f, 0.f, 0.f, 0.f};
#pragma unroll
            for (int k = 0; k < 25; ++k) {
#pragma unroll
                for (int c = 0; c < 5; ++c) acc[c] = fmaf(xi[k], sW[s][k][c], acc[c]);
            }
#pragma unroll
            for (int c = 0; c < 5; ++c) h[(s * N_NODES + i) * 5 + c] = acc[c];
            deg[s * N_NODES + i] = 1.0f;
        }
    }
}

// K2: deg[s][dst] += 1 for each edge (3 sets flattened)
__global__ void k2_degree(const int* __restrict__ ep,
                          const int* __restrict__ es,
                          const int* __restrict__ ev,
                          float* __restrict__ deg)
{
    long e = (long)blockIdx.x * blockDim.x + threadIdx.x;
    if (e >= 3L * N_EDGES) return;
    int s = (int)(e / N_EDGES);
    int i = (int)(e - (long)s * N_EDGES);
    const int* ei = (s == 0) ? ep : ((s == 1) ? es : ev);
    int dst = ei[N_EDGES + i];
    atomicAdd(&deg[s * N_NODES + dst], 1.0f);
}

// K3: accum[s][i][c] = h[s][i][c] / deg[s][i]  (self-loop term, norm = dinv^2 = 1/deg) + b_s[c]
__global__ void k3_accum_init(const float* __restrict__ h,
                              const float* __restrict__ deg,
                              const float* __restrict__ bp,
                              const float* __restrict__ bs,
                              const float* __restrict__ bv,
                              float* __restrict__ accum)
{
    int i = blockIdx.x * blockDim.x + threadIdx.x;
    if (i >= N_NODES) return;
#pragma unroll
    for (int s = 0; s < 3; ++s) {
        const float* b = (s == 0) ? bp : ((s == 1) ? bs : bv);
        float inv = 1.0f / deg[s * N_NODES + i];
#pragma unroll
        for (int c = 0; c < 5; ++c)
            accum[(s * N_NODES + i) * 5 + c] = h[(s * N_NODES + i) * 5 + c] * inv + b[c];
    }
}

// K4: accum[s][dst][c] += h[s][src][c] * rsqrt(deg[s][src]*deg[s][dst])
__global__ void k4_scatter(const int* __restrict__ ep,
                           const int* __restrict__ es,
                           const int* __restrict__ ev,
                           const float* __restrict__ h,
                           const float* __restrict__ deg,
                           float* __restrict__ accum)
{
    long e = (long)blockIdx.x * blockDim.x + threadIdx.x;
    if (e >= 3L * N_EDGES) return;
    int s = (int)(e / N_EDGES);
    int i = (int)(e - (long)s * N_EDGES);
    const int* ei = (s == 0) ? ep : ((s == 1) ? es : ev);
    int src = ei[i];
    int dst = ei[N_EDGES + i];
    float norm = rsqrtf(deg[s * N_NODES + src] * deg[s * N_NODES + dst]);
    const float* hp = h + (size_t)(s * N_NODES + src) * 5;
    float* ap = accum + (size_t)(s * N_NODES + dst) * 5;
#pragma unroll
    for (int c = 0; c < 5; ++c) atomicAdd(&ap[c], hp[c] * norm);
}

// K5: per-node fused MLP: leaky(concat) -> 15x10 leaky -> 10x5 -> 5x5 leaky -> 5x2
__global__ void k5_mlp(const float* __restrict__ accum,
                       const float* __restrict__ pw1, const float* __restrict__ pb1,
                       const float* __restrict__ pw2, const float* __restrict__ pb2,
                       const float* __restrict__ cw1, const float* __restrict__ cb1,
                       const float* __restrict__ cw2, const float* __restrict__ cb2,
                       float* __restrict__ out)
{
    // 150 + 10 + 50 + 5 + 25 + 5 + 10 + 2 = 257 floats of weights
    __shared__ float sw[257];
    for (int j = threadIdx.x; j < 257; j += blockDim.x) {
        float v;
        if (j < 150) v = pw1[j];
        else if (j < 160) v = pb1[j - 150];
        else if (j < 210) v = pw2[j - 160];
        else if (j < 215) v = pb2[j - 210];
        else if (j < 240) v = cw1[j - 215];
        else if (j < 245) v = cb1[j - 240];
        else if (j < 255) v = cw2[j - 245];
        else v = cb2[j - 255];
        sw[j] = v;
    }
    __syncthreads();
    const float* W1 = sw;         // [15][10]
    const float* B1 = sw + 150;   // [10]
    const float* W2 = sw + 160;   // [10][5]
    const float* B2 = sw + 210;   // [5]
    const float* C1 = sw + 215;   // [5][5]
    const float* D1 = sw + 240;   // [5]
    const float* C2 = sw + 245;   // [5][2]
    const float* D2 = sw + 255;   // [2]

    int i = blockIdx.x * blockDim.x + threadIdx.x;
    if (i >= N_NODES) return;

    float hin[15];
#pragma unroll
    for (int s = 0; s < 3; ++s)
#pragma unroll
        for (int c = 0; c < 5; ++c)
            hin[s * 5 + c] = leaky_f(accum[(size_t)(s * N_NODES + i) * 5 + c]);

    float h1[10];
#pragma unroll
    for (int o = 0; o < 10; ++o) h1[o] = B1[o];
#pragma unroll
    for (int k = 0; k < 15; ++k)
#pragma unroll
        for (int o = 0; o < 10; ++o) h1[o] = fmaf(hin[k], W1[k * 10 + o], h1[o]);
#pragma unroll
    for (int o = 0; o < 10; ++o) h1[o] = leaky_f(h1[o]);

    float h2[5];
#pragma unroll
    for (int o = 0; o < 5; ++o) h2[o] = B2[o];
#pragma unroll
    for (int k = 0; k < 10; ++k)
#pragma unroll
        for (int o = 0; o < 5; ++o) h2[o] = fmaf(h1[k], W2[k * 5 + o], h2[o]);

    float h3[5];
#pragma unroll
    for (int o = 0; o < 5; ++o) h3[o] = D1[o];
#pragma unroll
    for (int k = 0; k < 5; ++k)
#pragma unroll
        for (int o = 0; o < 5; ++o) h3[o] = fmaf(h2[k], C1[k * 5 + o], h3[o]);
#pragma unroll
    for (int o = 0; o < 5; ++o) h3[o] = leaky_f(h3[o]);

    float o0 = D2[0], o1 = D2[1];
#pragma unroll
    for (int k = 0; k < 5; ++k) {
        o0 = fmaf(h3[k], C2[k * 2 + 0], o0);
        o1 = fmaf(h3[k], C2[k * 2 + 1], o1);
    }
    out[(size_t)i * 2 + 0] = o0;
    out[(size_t)i * 2 + 1] = o1;
}

extern "C" void kernel_launch(void* const* d_in, const int* in_sizes, int n_in,
                              void* d_out, int out_size, void* d_ws, size_t ws_size,
                              hipStream_t stream)
{
    const float* x   = (const float*)d_in[0];
    const int*   ep  = (const int*)d_in[1];
    const int*   es  = (const int*)d_in[2];
    const int*   ev  = (const int*)d_in[3];
    const float* Wp  = (const float*)d_in[4];
    const float* bp  = (const float*)d_in[5];
    const float* Ws  = (const float*)d_in[6];
    const float* bs  = (const float*)d_in[7];
    const float* Wv  = (const float*)d_in[8];
    const float* bv  = (const float*)d_in[9];
    const float* pw1 = (const float*)d_in[10];
    const float* pb1 = (const float*)d_in[11];
    const float* pw2 = (const float*)d_in[12];
    const float* pb2 = (const float*)d_in[13];
    const float* cw1 = (const float*)d_in[14];
    const float* cb1 = (const float*)d_in[15];
    const float* cw2 = (const float*)d_in[16];
    const float* cb2 = (const float*)d_in[17];

    float* out = (float*)d_out;

    // workspace layout (floats): h[3*N*5] | deg[3*N] | accum[3*N*5]
    float* ws    = (float*)d_ws;
    float* h     = ws;                       // 7.5M floats = 30MB
    float* deg   = h + 3L * N_NODES * 5;     // 1.5M floats = 6MB
    float* accum = deg + 3L * N_NODES;       // 7.5M floats = 30MB

    const int BLK = 256;
    int gridN = (N_NODES + BLK - 1) / BLK;
    long totalE = 3L * N_EDGES;
    int gridE = (int)((totalE + BLK - 1) / BLK);

    k1_gemm_deginit<<<gridN, BLK, 0, stream>>>(x, Wp, Ws, Wv, h, deg);
    k2_degree<<<gridE, BLK, 0, stream>>>(ep, es, ev, deg);
    k3_accum_init<<<gridN, BLK, 0, stream>>>(h, deg, bp, bs, bv, accum);
    k4_scatter<<<gridE, BLK, 0, stream>>>(ep, es, ev, h, deg, accum);
    k5_mlp<<<gridN, BLK, 0, stream>>>(accum, pw1, pb1, pw2, pb2, cw1, cb1, cw2, cb2, out);
}

// Round 2
// 1337.912 us; speedup vs baseline: 5.5095x; 5.5095x over previous
//
#include <hip/hip_runtime.h>

#define N_NODES 500000
#define N_EDGES 8000000
#define W_BKT 1024
#define NBKT 489                      // ceil(N_NODES / W_BKT)
#define P1_BLK 256
#define P1_EPT 128
#define P1_CHUNK (P1_BLK * P1_EPT)    // 32768 edges per block
#define P1_BLOCKS ((N_EDGES + P1_CHUNK - 1) / P1_CHUNK)  // 245

typedef unsigned int uint;

__device__ __forceinline__ float leaky_f(float x) { return x > 0.0f ? x : 0.1f * x; }

// ---------------------------------------------------------------------------
// FAST PATH (counting-sort by dst bucket + LDS aggregation, no global fp atomics)
// ---------------------------------------------------------------------------

// zero the bucket counters
__global__ void k0_zero(uint* __restrict__ counts) {
    int t = blockIdx.x * blockDim.x + threadIdx.x;
    if (t < 3 * NBKT) counts[t] = 0;
}

// hx[s][i][0..4] = (x @ W_s)[i], hx[s][i][5] = rsqrt(deg) (written later), stride 8
__global__ void k1_hx(const float* __restrict__ x,
                      const float* __restrict__ Wp,
                      const float* __restrict__ Ws,
                      const float* __restrict__ Wv,
                      float* __restrict__ hx)
{
    __shared__ float sW[3][25][5];
    int t = threadIdx.x;
    if (t < 125) {
        sW[0][t / 5][t % 5] = Wp[t];
        sW[1][t / 5][t % 5] = Ws[t];
        sW[2][t / 5][t % 5] = Wv[t];
    }
    __syncthreads();
    int i = blockIdx.x * blockDim.x + t;
    if (i >= N_NODES) return;
    float xi[25];
#pragma unroll
    for (int k = 0; k < 25; ++k) xi[k] = x[i * 25 + k];
#pragma unroll
    for (int s = 0; s < 3; ++s) {
        float acc[5] = {0.f, 0.f, 0.f, 0.f, 0.f};
#pragma unroll
        for (int k = 0; k < 25; ++k)
#pragma unroll
            for (int c = 0; c < 5; ++c) acc[c] = fmaf(xi[k], sW[s][k][c], acc[c]);
        float* hp = &hx[((size_t)s * N_NODES + i) * 8];
        float4 v0 = make_float4(acc[0], acc[1], acc[2], acc[3]);
        float4 v1 = make_float4(acc[4], 0.f, 0.f, 0.f);
        *(float4*)hp = v0;
        *(float4*)(hp + 4) = v1;
    }
}

// P1a: per-bucket edge counts (LDS histogram, then one global add per bucket/block)
__global__ void p1_count(const int* __restrict__ ep,
                         const int* __restrict__ es,
                         const int* __restrict__ ev,
                         uint* __restrict__ counts)
{
    int s = blockIdx.y;
    const int* ei = (s == 0) ? ep : ((s == 1) ? es : ev);
    const int* dstp = ei + N_EDGES;
    __shared__ uint hist[NBKT];
    for (int b = threadIdx.x; b < NBKT; b += P1_BLK) hist[b] = 0;
    __syncthreads();
    int start = blockIdx.x * P1_CHUNK;
#pragma unroll 4
    for (int j = 0; j < P1_EPT; ++j) {
        int idx = start + j * P1_BLK + threadIdx.x;
        if (idx < N_EDGES) atomicAdd(&hist[((uint)dstp[idx]) >> 10], 1u);
    }
    __syncthreads();
    for (int b = threadIdx.x; b < NBKT; b += P1_BLK)
        if (hist[b]) atomicAdd(&counts[s * NBKT + b], hist[b]);
}

// P1b: exclusive scan of counts -> base, cursor (3 tiny sequential scans)
__global__ void p1_scan(const uint* __restrict__ counts,
                        uint* __restrict__ base,
                        uint* __restrict__ cursor)
{
    int s = threadIdx.x;
    if (s < 3) {
        uint run = 0;
        for (int b = 0; b < NBKT; ++b) {
            uint c = counts[s * NBKT + b];
            base[s * NBKT + b] = run;
            cursor[s * NBKT + b] = run;
            run += c;
        }
    }
}

// P1c: scatter edges into bucket-sorted array, packed (local_dst<<19 | src)
__global__ void p1_scatter(const int* __restrict__ ep,
                           const int* __restrict__ es,
                           const int* __restrict__ ev,
                           uint* __restrict__ cursor,
                           uint* __restrict__ parts)
{
    int s = blockIdx.y;
    const int* ei = (s == 0) ? ep : ((s == 1) ? es : ev);
    const int* srcp = ei;
    const int* dstp = ei + N_EDGES;
    uint* part = parts + (size_t)s * N_EDGES;
    __shared__ uint hist[NBKT];
    __shared__ uint bbase[NBKT];
    for (int b = threadIdx.x; b < NBKT; b += P1_BLK) hist[b] = 0;
    __syncthreads();
    int start = blockIdx.x * P1_CHUNK;
#pragma unroll 4
    for (int j = 0; j < P1_EPT; ++j) {
        int idx = start + j * P1_BLK + threadIdx.x;
        if (idx < N_EDGES) atomicAdd(&hist[((uint)dstp[idx]) >> 10], 1u);
    }
    __syncthreads();
    for (int b = threadIdx.x; b < NBKT; b += P1_BLK) {
        uint c = hist[b];
        if (c) bbase[b] = atomicAdd(&cursor[s * NBKT + b], c);
        hist[b] = 0;
    }
    __syncthreads();
#pragma unroll 4
    for (int j = 0; j < P1_EPT; ++j) {
        int idx = start + j * P1_BLK + threadIdx.x;
        if (idx < N_EDGES) {
            uint dst = (uint)dstp[idx];
            uint b = dst >> 10;
            uint r = atomicAdd(&hist[b], 1u);
            part[bbase[b] + r] = ((dst & 1023u) << 19) | (uint)srcp[idx];
        }
    }
}

// P2a: per-bucket degree via LDS histogram -> hx[s][node][5] = rsqrt(1+deg_in)
__global__ void p2_degree(const uint* __restrict__ parts,
                          const uint* __restrict__ base,
                          const uint* __restrict__ counts,
                          float* __restrict__ hx)
{
    int b = blockIdx.x;
    __shared__ uint cnt[3 * W_BKT];
    for (int t = threadIdx.x; t < 3 * W_BKT; t += blockDim.x) cnt[t] = 0;
    __syncthreads();
    for (int s = 0; s < 3; ++s) {
        uint s0 = base[s * NBKT + b], c0 = counts[s * NBKT + b];
        const uint* part = parts + (size_t)s * N_EDGES + s0;
        for (uint i = threadIdx.x; i < c0; i += blockDim.x)
            atomicAdd(&cnt[s * W_BKT + (part[i] >> 19)], 1u);
    }
    __syncthreads();
    int nb = b << 10;
    for (int n = threadIdx.x; n < W_BKT; n += blockDim.x) {
        int node = nb + n;
        if (node < N_NODES) {
#pragma unroll
            for (int s = 0; s < 3; ++s)
                hx[((size_t)s * N_NODES + node) * 8 + 5] =
                    rsqrtf(1.0f + (float)cnt[s * W_BKT + n]);
        }
    }
}

// P2b: per-bucket aggregate in LDS (self-loop init + edge LDS-atomics) + fused MLP
__global__ __launch_bounds__(512) void p2_agg_mlp(
    const uint* __restrict__ parts, const uint* __restrict__ base,
    const uint* __restrict__ counts, const float* __restrict__ hx,
    const float* __restrict__ bp, const float* __restrict__ bs, const float* __restrict__ bv,
    const float* __restrict__ pw1, const float* __restrict__ pb1,
    const float* __restrict__ pw2, const float* __restrict__ pb2,
    const float* __restrict__ cw1, const float* __restrict__ cb1,
    const float* __restrict__ cw2, const float* __restrict__ cb2,
    float* __restrict__ out)
{
    __shared__ float acc[3 * W_BKT * 5];   // 60 KB
    __shared__ float wts[272];
    int tid = threadIdx.x;
    for (int j = tid; j < 272; j += blockDim.x) {
        float v;
        if (j < 150) v = pw1[j];
        else if (j < 160) v = pb1[j - 150];
        else if (j < 210) v = pw2[j - 160];
        else if (j < 215) v = pb2[j - 210];
        else if (j < 240) v = cw1[j - 215];
        else if (j < 245) v = cb1[j - 240];
        else if (j < 255) v = cw2[j - 245];
        else if (j < 257) v = cb2[j - 255];
        else if (j < 262) v = bp[j - 257];
        else if (j < 267) v = bs[j - 262];
        else v = bv[j - 267];
        wts[j] = v;
    }
    int b = blockIdx.x;
    int nb = b << 10;
    __syncthreads();

    // self-loop + bias init: acc = h/deg + b
    for (int t = tid; t < 3 * W_BKT; t += blockDim.x) {
        int s = t >> 10;
        int n = t & (W_BKT - 1);
        int node = nb + n;
        float* a = &acc[t * 5];
        if (node < N_NODES) {
            const float* hp = &hx[((size_t)s * N_NODES + node) * 8];
            float rd = hp[5];
            float inv = rd * rd;
            const float* bb = &wts[257 + s * 5];
#pragma unroll
            for (int c = 0; c < 5; ++c) a[c] = fmaf(hp[c], inv, bb[c]);
        } else {
#pragma unroll
            for (int c = 0; c < 5; ++c) a[c] = 0.f;
        }
    }
    __syncthreads();

    // edge aggregation into LDS
    for (int s = 0; s < 3; ++s) {
        uint s0 = base[s * NBKT + b], c0 = counts[s * NBKT + b];
        const uint* part = parts + (size_t)s * N_EDGES + s0;
        const float* hxs = hx + (size_t)s * N_NODES * 8;
        float* accs = acc + s * W_BKT * 5;
        for (uint i = tid; i < c0; i += blockDim.x) {
            uint p = part[i];
            uint src = p & 0x7FFFFu;
            uint ld = p >> 19;
            const float* hp = &hxs[(size_t)src * 8];
            float norm = hp[5] * hxs[((size_t)(nb + ld)) * 8 + 5];
            float* a = &accs[ld * 5];
#pragma unroll
            for (int c = 0; c < 5; ++c) atomicAdd(&a[c], hp[c] * norm);
        }
    }
    __syncthreads();

    // fused MLP epilogue
    const float* W1 = wts;          // [15][10]
    const float* B1 = wts + 150;
    const float* W2 = wts + 160;    // [10][5]
    const float* B2 = wts + 210;
    const float* C1 = wts + 215;    // [5][5]
    const float* D1 = wts + 240;
    const float* C2 = wts + 245;    // [5][2]
    const float* D2 = wts + 255;
    for (int n = tid; n < W_BKT; n += blockDim.x) {
        int node = nb + n;
        if (node >= N_NODES) break;
        float hin[15];
#pragma unroll
        for (int s = 0; s < 3; ++s)
#pragma unroll
            for (int c = 0; c < 5; ++c)
                hin[s * 5 + c] = leaky_f(acc[(s * W_BKT + n) * 5 + c]);
        float h1[10];
#pragma unroll
        for (int o = 0; o < 10; ++o) h1[o] = B1[o];
#pragma unroll
        for (int k = 0; k < 15; ++k)
#pragma unroll
            for (int o = 0; o < 10; ++o) h1[o] = fmaf(hin[k], W1[k * 10 + o], h1[o]);
#pragma unroll
        for (int o = 0; o < 10; ++o) h1[o] = leaky_f(h1[o]);
        float h2[5];
#pragma unroll
        for (int o = 0; o < 5; ++o) h2[o] = B2[o];
#pragma unroll
        for (int k = 0; k < 10; ++k)
#pragma unroll
            for (int o = 0; o < 5; ++o) h2[o] = fmaf(h1[k], W2[k * 5 + o], h2[o]);
        float h3[5];
#pragma unroll
        for (int o = 0; o < 5; ++o) h3[o] = D1[o];
#pragma unroll
        for (int k = 0; k < 5; ++k)
#pragma unroll
            for (int o = 0; o < 5; ++o) h3[o] = fmaf(h2[k], C1[k * 5 + o], h3[o]);
#pragma unroll
        for (int o = 0; o < 5; ++o) h3[o] = leaky_f(h3[o]);
        float o0 = D2[0], o1 = D2[1];
#pragma unroll
        for (int k = 0; k < 5; ++k) {
            o0 = fmaf(h3[k], C2[k * 2 + 0], o0);
            o1 = fmaf(h3[k], C2[k * 2 + 1], o1);
        }
        out[(size_t)node * 2 + 0] = o0;
        out[(size_t)node * 2 + 1] = o1;
    }
}

// ---------------------------------------------------------------------------
// FALLBACK PATH (round-0 global-atomic version, used only if ws is too small)
// ---------------------------------------------------------------------------

__global__ void k1_gemm_deginit(const float* __restrict__ x,
                                const float* __restrict__ Wp,
                                const float* __restrict__ Ws,
                                const float* __restrict__ Wv,
                                float* __restrict__ h, float* __restrict__ deg)
{
    __shared__ float sW[3][25][5];
    int t = threadIdx.x;
    if (t < 125) { sW[0][t/5][t%5]=Wp[t]; sW[1][t/5][t%5]=Ws[t]; sW[2][t/5][t%5]=Wv[t]; }
    __syncthreads();
    for (int i = blockIdx.x * blockDim.x + t; i < N_NODES; i += gridDim.x * blockDim.x) {
        float xi[25];
#pragma unroll
        for (int k = 0; k < 25; ++k) xi[k] = x[i * 25 + k];
#pragma unroll
        for (int s = 0; s < 3; ++s) {
            float acc[5] = {0.f,0.f,0.f,0.f,0.f};
#pragma unroll
            for (int k = 0; k < 25; ++k)
#pragma unroll
                for (int c = 0; c < 5; ++c) acc[c] = fmaf(xi[k], sW[s][k][c], acc[c]);
#pragma unroll
            for (int c = 0; c < 5; ++c) h[(s * N_NODES + i) * 5 + c] = acc[c];
            deg[s * N_NODES + i] = 1.0f;
        }
    }
}

__global__ void k2_degree(const int* __restrict__ ep, const int* __restrict__ es,
                          const int* __restrict__ ev, float* __restrict__ deg)
{
    long e = (long)blockIdx.x * blockDim.x + threadIdx.x;
    if (e >= 3L * N_EDGES) return;
    int s = (int)(e / N_EDGES);
    int i = (int)(e - (long)s * N_EDGES);
    const int* ei = (s == 0) ? ep : ((s == 1) ? es : ev);
    atomicAdd(&deg[s * N_NODES + ei[N_EDGES + i]], 1.0f);
}

__global__ void k3_accum_init(const float* __restrict__ h, const float* __restrict__ deg,
                              const float* __restrict__ bp, const float* __restrict__ bs,
                              const float* __restrict__ bv, float* __restrict__ accum)
{
    int i = blockIdx.x * blockDim.x + threadIdx.x;
    if (i >= N_NODES) return;
#pragma unroll
    for (int s = 0; s < 3; ++s) {
        const float* b = (s == 0) ? bp : ((s == 1) ? bs : bv);
        float inv = 1.0f / deg[s * N_NODES + i];
#pragma unroll
        for (int c = 0; c < 5; ++c)
            accum[(s * N_NODES + i) * 5 + c] = h[(s * N_NODES + i) * 5 + c] * inv + b[c];
    }
}

__global__ void k4_scatter(const int* __restrict__ ep, const int* __restrict__ es,
                           const int* __restrict__ ev, const float* __restrict__ h,
                           const float* __restrict__ deg, float* __restrict__ accum)
{
    long e = (long)blockIdx.x * blockDim.x + threadIdx.x;
    if (e >= 3L * N_EDGES) return;
    int s = (int)(e / N_EDGES);
    int i = (int)(e - (long)s * N_EDGES);
    const int* ei = (s == 0) ? ep : ((s == 1) ? es : ev);
    int src = ei[i];
    int dst = ei[N_EDGES + i];
    float norm = rsqrtf(deg[s * N_NODES + src] * deg[s * N_NODES + dst]);
    const float* hp = h + (size_t)(s * N_NODES + src) * 5;
    float* ap = accum + (size_t)(s * N_NODES + dst) * 5;
#pragma unroll
    for (int c = 0; c < 5; ++c) atomicAdd(&ap[c], hp[c] * norm);
}

__global__ void k5_mlp(const float* __restrict__ accum,
                       const float* __restrict__ pw1, const float* __restrict__ pb1,
                       const float* __restrict__ pw2, const float* __restrict__ pb2,
                       const float* __restrict__ cw1, const float* __restrict__ cb1,
                       const float* __restrict__ cw2, const float* __restrict__ cb2,
                       float* __restrict__ out)
{
    __shared__ float sw[257];
    for (int j = threadIdx.x; j < 257; j += blockDim.x) {
        float v;
        if (j < 150) v = pw1[j];
        else if (j < 160) v = pb1[j - 150];
        else if (j < 210) v = pw2[j - 160];
        else if (j < 215) v = pb2[j - 210];
        else if (j < 240) v = cw1[j - 215];
        else if (j < 245) v = cb1[j - 240];
        else if (j < 255) v = cw2[j - 245];
        else v = cb2[j - 255];
        sw[j] = v;
    }
    __syncthreads();
    const float* W1 = sw; const float* B1 = sw + 150; const float* W2 = sw + 160;
    const float* B2 = sw + 210; const float* C1 = sw + 215; const float* D1 = sw + 240;
    const float* C2 = sw + 245; const float* D2 = sw + 255;
    int i = blockIdx.x * blockDim.x + threadIdx.x;
    if (i >= N_NODES) return;
    float hin[15];
#pragma unroll
    for (int s = 0; s < 3; ++s)
#pragma unroll
        for (int c = 0; c < 5; ++c)
            hin[s * 5 + c] = leaky_f(accum[(size_t)(s * N_NODES + i) * 5 + c]);
    float h1[10];
#pragma unroll
    for (int o = 0; o < 10; ++o) h1[o] = B1[o];
#pragma unroll
    for (int k = 0; k < 15; ++k)
#pragma unroll
        for (int o = 0; o < 10; ++o) h1[o] = fmaf(hin[k], W1[k * 10 + o], h1[o]);
#pragma unroll
    for (int o = 0; o < 10; ++o) h1[o] = leaky_f(h1[o]);
    float h2[5];
#pragma unroll
    for (int o = 0; o < 5; ++o) h2[o] = B2[o];
#pragma unroll
    for (int k = 0; k < 10; ++k)
#pragma unroll
        for (int o = 0; o < 5; ++o) h2[o] = fmaf(h1[k], W2[k * 5 + o], h2[o]);
    float h3[5];
#pragma unroll
    for (int o = 0; o < 5; ++o) h3[o] = D1[o];
#pragma unroll
    for (int k = 0; k < 5; ++k)
#pragma unroll
        for (int o = 0; o < 5; ++o) h3[o] = fmaf(h2[k], C1[k * 5 + o], h3[o]);
#pragma unroll
    for (int o = 0; o < 5; ++o) h3[o] = leaky_f(h3[o]);
    float o0 = D2[0], o1 = D2[1];
#pragma unroll
    for (int k = 0; k < 5; ++k) {
        o0 = fmaf(h3[k], C2[k * 2 + 0], o0);
        o1 = fmaf(h3[k], C2[k * 2 + 1], o1);
    }
    out[(size_t)i * 2 + 0] = o0;
    out[(size_t)i * 2 + 1] = o1;
}

// ---------------------------------------------------------------------------

extern "C" void kernel_launch(void* const* d_in, const int* in_sizes, int n_in,
                              void* d_out, int out_size, void* d_ws, size_t ws_size,
                              hipStream_t stream)
{
    const float* x   = (const float*)d_in[0];
    const int*   ep  = (const int*)d_in[1];
    const int*   es  = (const int*)d_in[2];
    const int*   ev  = (const int*)d_in[3];
    const float* Wp  = (const float*)d_in[4];
    const float* bp  = (const float*)d_in[5];
    const float* Ws  = (const float*)d_in[6];
    const float* bs  = (const float*)d_in[7];
    const float* Wv  = (const float*)d_in[8];
    const float* bv  = (const float*)d_in[9];
    const float* pw1 = (const float*)d_in[10];
    const float* pb1 = (const float*)d_in[11];
    const float* pw2 = (const float*)d_in[12];
    const float* pb2 = (const float*)d_in[13];
    const float* cw1 = (const float*)d_in[14];
    const float* cb1 = (const float*)d_in[15];
    const float* cw2 = (const float*)d_in[16];
    const float* cb2 = (const float*)d_in[17];
    float* out = (float*)d_out;

    const size_t HX_ELEMS    = 3ULL * N_NODES * 8;   // 12M floats, 48 MB
    const size_t PARTS_ELEMS = 3ULL * N_EDGES;       // 24M uints,  96 MB
    const size_t META_ELEMS  = 3ULL * 3 * NBKT;
    const size_t NEED = (HX_ELEMS * 4) + (PARTS_ELEMS * 4) + (META_ELEMS * 4) + 256;

    if (ws_size >= NEED) {
        float* hx     = (float*)d_ws;
        uint*  parts  = (uint*)(hx + HX_ELEMS);
        uint*  counts = parts + PARTS_ELEMS;
        uint*  base   = counts + 3 * NBKT;
        uint*  cursor = base + 3 * NBKT;

        int gridN = (N_NODES + 255) / 256;
        dim3 gridP1(P1_BLOCKS, 3);

        k0_zero<<<(3 * NBKT + 255) / 256, 256, 0, stream>>>(counts);
        k1_hx<<<gridN, 256, 0, stream>>>(x, Wp, Ws, Wv, hx);
        p1_count<<<gridP1, P1_BLK, 0, stream>>>(ep, es, ev, counts);
        p1_scan<<<1, 64, 0, stream>>>(counts, base, cursor);
        p1_scatter<<<gridP1, P1_BLK, 0, stream>>>(ep, es, ev, cursor, parts);
        p2_degree<<<NBKT, 256, 0, stream>>>(parts, base, counts, hx);
        p2_agg_mlp<<<NBKT, 512, 0, stream>>>(parts, base, counts, hx,
                                             bp, bs, bv,
                                             pw1, pb1, pw2, pb2,
                                             cw1, cb1, cw2, cb2, out);
    } else {
        // fallback: round-0 global-atomic pipeline (needs 66 MB)
        float* ws    = (float*)d_ws;
        float* h     = ws;
        float* deg   = h + 3L * N_NODES * 5;
        float* accum = deg + 3L * N_NODES;

        const int BLK = 256;
        int gridN = (N_NODES + BLK - 1) / BLK;
        long totalE = 3L * N_EDGES;
        int gridE = (int)((totalE + BLK - 1) / BLK);

        k1_gemm_deginit<<<gridN, BLK, 0, stream>>>(x, Wp, Ws, Wv, h, deg);
        k2_degree<<<gridE, BLK, 0, stream>>>(ep, es, ev, deg);
        k3_accum_init<<<gridN, BLK, 0, stream>>>(h, deg, bp, bs, bv, accum);
        k4_scatter<<<gridE, BLK, 0, stream>>>(ep, es, ev, h, deg, accum);
        k5_mlp<<<gridN, BLK, 0, stream>>>(accum, pw1, pb1, pw2, pb2, cw1, cb1, cw2, cb2, out);
    }
}